// Round 2
// baseline (66.330 us; speedup 1.0000x reference)
//
#include <hip/hip_runtime.h>
#include <math.h>

#define IMG    256
#define NPTS   320
#define CHUNKS 8
#define SPC    40          // NPTS / CHUNKS
#define NBLK   1024        // 32x32 blocks of 8x8 pixels

// ---------------------------------------------------------------------------
// Render: one ray per (pixel, depth-chunk); block = 8x8 pixel tile x 8 chunks.
// Writes pre-normalization screen value to outv[w*256+h] and per-block
// {sum, sumsq, min, max} partials for the normalization constants.
// ---------------------------------------------------------------------------
__global__ __launch_bounds__(512)
void xray_render(const float* __restrict__ vol,
                 const float* __restrict__ Rm,
                 const float* __restrict__ Tv,
                 const float* __restrict__ fc,
                 float* __restrict__ outv,
                 float* __restrict__ partials)
{
    const int tid = threadIdx.x;
    const int p   = tid & 63;        // pixel within 8x8 tile
    const int c   = tid >> 6;        // depth chunk 0..7
    const int w   = (blockIdx.x << 3) + (p & 7);
    const int h   = (blockIdx.y << 3) + (p >> 3);

    const float f   = fc[0];
    const float r00 = Rm[0], r01 = Rm[1], r02 = Rm[2];
    const float r10 = Rm[3], r11 = Rm[4], r12 = Rm[5];
    const float r20 = Rm[6], r21 = Rm[7], r22 = Rm[8];
    const float t0  = Tv[0], t1  = Tv[1], t2  = Tv[2];

    // xs[w] = 255/256 - w/128 ; ys[h] likewise (linspace 1-1/256 .. -1+1/256)
    const float invf = 1.0f / f;
    const float px = 0.99609375f - (float)w * 0.0078125f;
    const float py = 0.99609375f - (float)h * 0.0078125f;
    const float dcx = px * invf, dcy = py * invf;   // cam dir = (dcx,dcy,1)*d

    // world(d) = R @ (cam - T) = d * (R@dir) - R@T
    const float dwx = r00*dcx + r01*dcy + r02;
    const float dwy = r10*dcx + r11*dcy + r12;
    const float dwz = r20*dcx + r21*dcy + r22;
    const float ox  = -(r00*t0 + r01*t1 + r02*t2);
    const float oy  = -(r10*t0 + r11*t1 + r12*t2);
    const float oz  = -(r20*t0 + r21*t1 + r22*t2);

    // grid coords: g = 128*world + 127.5 (scale = 255/256 on every axis)
    // depths: d_i = 3 + i*(6/319)  ->  g_i = G0 + i*GS
    const float g0x = fmaf(384.0f, dwx, fmaf(128.0f, ox, 127.5f));
    const float g0y = fmaf(384.0f, dwy, fmaf(128.0f, oy, 127.5f));
    const float g0z = fmaf(384.0f, dwz, fmaf(128.0f, oz, 127.5f));
    const float K   = 768.0f / 319.0f;   // 128 * 6/319
    const float gsx = K*dwx, gsy = K*dwy, gsz = K*dwz;

    // ray-box clip: coverage > 0 only where g in (-1, 256) on every axis
    float raylo = -1e30f, rayhi = 1e30f;
    {
        const float g0a[3] = {g0x, g0y, g0z};
        const float gsa[3] = {gsx, gsy, gsz};
        #pragma unroll
        for (int a = 0; a < 3; ++a) {
            if (fabsf(gsa[a]) > 1e-9f) {
                float u = (-1.0f  - g0a[a]) / gsa[a];
                float v = (256.0f - g0a[a]) / gsa[a];
                raylo = fmaxf(raylo, fminf(u, v));
                rayhi = fminf(rayhi, fmaxf(u, v));
            } else if (!(g0a[a] > -1.0f && g0a[a] < 256.0f)) {
                raylo = 1e30f; rayhi = -1e30f;
            }
        }
    }
    // 1-sample safety margin, then clamp to this chunk's index range
    float a0 = fmaxf(raylo - 1.0f, (float)(c * SPC));
    float a1 = fminf(rayhi + 1.0f, (float)(c * SPC + SPC - 1));
    a0 = fminf(fmaxf(a0, 0.0f),  400.0f);
    a1 = fminf(fmaxf(a1, -1.0f), 400.0f);
    const int i0 = (int)ceilf(a0);
    const int i1 = (int)floorf(a1);

    float feat = 0.0f, Tc = 1.0f, pr = 1.0f;

    for (int i = i0; i <= i1; ++i) {
        const float fi = (float)i;
        const float gx = fmaf(fi, gsx, g0x);
        const float gy = fmaf(fi, gsy, g0y);
        const float gz = fmaf(fi, gsz, g0z);
        const float xf = floorf(gx), yf = floorf(gy), zf = floorf(gz);
        const float fx = gx - xf, fy = gy - yf, fz = gz - zf;
        const int ix = (int)xf, iy = (int)yf, iz = (int)zf;

        if ((unsigned)ix <= 254u && (unsigned)iy <= 254u && (unsigned)iz <= 254u) {
            // fully inside: coverage == 1, dens == 0.1 exactly
            const float* b = vol + ((iz << 16) + (iy << 8) + ix);
            const float v000 = b[0],     v001 = b[1];
            const float v010 = b[256],   v011 = b[257];
            const float v100 = b[65536], v101 = b[65537];
            const float v110 = b[65792], v111 = b[65793];
            const float c00 = fmaf(fx, v001 - v000, v000);
            const float c01 = fmaf(fx, v011 - v010, v010);
            const float c10 = fmaf(fx, v101 - v100, v100);
            const float c11 = fmaf(fx, v111 - v110, v110);
            const float c0  = fmaf(fy, c01 - c00, c00);
            const float c1  = fmaf(fy, c11 - c10, c10);
            const float gray = fmaf(fz, c1 - c0, c0);
            feat = fmaf(0.1f * Tc, gray, feat);
            Tc *= 0.9f;     // (1 + 1e-10 - 0.1) rounds to 0.9f in fp32
            pr *= 0.9f;
        } else {
            // boundary shell: masked weights, clamped indices
            const float wx0 = (ix >= 0  && ix <= 255) ? (1.0f - fx) : 0.0f;
            const float wx1 = (ix >= -1 && ix <= 254) ? fx          : 0.0f;
            const float wy0 = (iy >= 0  && iy <= 255) ? (1.0f - fy) : 0.0f;
            const float wy1 = (iy >= -1 && iy <= 254) ? fy          : 0.0f;
            const float wz0 = (iz >= 0  && iz <= 255) ? (1.0f - fz) : 0.0f;
            const float wz1 = (iz >= -1 && iz <= 254) ? fz          : 0.0f;
            const float cov = (wx0 + wx1) * (wy0 + wy1) * (wz0 + wz1);
            if (cov > 0.0f) {
                const int x0 = min(max(ix, 0), 255),   x1 = min(max(ix + 1, 0), 255);
                const int y0 = min(max(iy, 0), 255),   y1 = min(max(iy + 1, 0), 255);
                const int z0 = min(max(iz, 0), 255),   z1 = min(max(iz + 1, 0), 255);
                const float* bz0 = vol + (z0 << 16);
                const float* bz1 = vol + (z1 << 16);
                const int ry0 = y0 << 8, ry1 = y1 << 8;
                const float s0 = (bz0[ry0 + x0]*wx0 + bz0[ry0 + x1]*wx1) * wy0
                               + (bz0[ry1 + x0]*wx0 + bz0[ry1 + x1]*wx1) * wy1;
                const float s1 = (bz1[ry0 + x0]*wx0 + bz1[ry0 + x1]*wx1) * wy0
                               + (bz1[ry1 + x0]*wx0 + bz1[ry1 + x1]*wx1) * wy1;
                const float gray = s0 * wz0 + s1 * wz1;
                const float dens = 0.1f * cov;
                feat = fmaf(dens * Tc, gray, feat);
                const float m = 1.0f - dens;
                Tc *= m;
                pr *= m;
            }
        }
    }

    // combine the 8 depth chunks per pixel:
    // feat = f0 + T0*(f1 + T1*(f2 + ...)),  prod = pr0*pr1*...
    __shared__ float sf[CHUNKS][64];
    __shared__ float sT[CHUNKS][64];
    __shared__ float sp[CHUNKS][64];
    sf[c][p] = feat; sT[c][p] = Tc; sp[c][p] = pr;
    __syncthreads();

    if (tid < 64) {
        float F = sf[CHUNKS - 1][p];
        #pragma unroll
        for (int j = CHUNKS - 2; j >= 0; --j) F = fmaf(sT[j][p], F, sf[j][p]);
        float PR = sp[0][p];
        #pragma unroll
        for (int j = 1; j < CHUNKS; ++j) PR *= sp[j][p];

        const float screen = fmaf(3.0f, F, 1.0f - PR) * 0.25f;
        outv[(w << 8) + h] = screen;   // transposed output layout

        float s = screen, s2 = screen * screen, mn = screen, mx = screen;
        #pragma unroll
        for (int o = 32; o; o >>= 1) {
            s  += __shfl_xor(s,  o);
            s2 += __shfl_xor(s2, o);
            mn  = fminf(mn, __shfl_xor(mn, o));
            mx  = fmaxf(mx, __shfl_xor(mx, o));
        }
        if (p == 0) {
            const int bid = (blockIdx.y << 5) + blockIdx.x;
            partials[bid * 4 + 0] = s;
            partials[bid * 4 + 1] = s2;
            partials[bid * 4 + 2] = mn;
            partials[bid * 4 + 3] = mx;
        }
    }
}

// ---------------------------------------------------------------------------
// Finalize: reduce 1024 block partials; emit affine (offset, 1/denom).
// out = (v - vmin + 1e-8*(std+1e-8)) / (vmax - vmin + 1e-8*(std+1e-8))
// (the mean cancels algebraically)
// ---------------------------------------------------------------------------
__global__ __launch_bounds__(256)
void xray_finalize(const float* __restrict__ partials, float* __restrict__ scal)
{
    const int t = threadIdx.x;
    double s = 0.0, s2 = 0.0;
    float mn = 1e30f, mx = -1e30f;
    for (int j = t; j < NBLK; j += 256) {
        s  += (double)partials[j * 4 + 0];
        s2 += (double)partials[j * 4 + 1];
        mn  = fminf(mn, partials[j * 4 + 2]);
        mx  = fmaxf(mx, partials[j * 4 + 3]);
    }
    for (int o = 32; o; o >>= 1) {
        s  += __shfl_xor(s,  o);
        s2 += __shfl_xor(s2, o);
        mn  = fminf(mn, __shfl_xor(mn, o));
        mx  = fmaxf(mx, __shfl_xor(mx, o));
    }
    __shared__ double ls[4], ls2[4];
    __shared__ float  lmn[4], lmx[4];
    const int wid = t >> 6, lane = t & 63;
    if (lane == 0) { ls[wid] = s; ls2[wid] = s2; lmn[wid] = mn; lmx[wid] = mx; }
    __syncthreads();
    if (t == 0) {
        const double S  = ls[0] + ls[1] + ls[2] + ls[3];
        const double S2 = ls2[0] + ls2[1] + ls2[2] + ls2[3];
        const float MN = fminf(fminf(lmn[0], lmn[1]), fminf(lmn[2], lmn[3]));
        const float MX = fmaxf(fmaxf(lmx[0], lmx[1]), fmaxf(lmx[2], lmx[3]));
        const double N   = 65536.0;
        double var = (S2 - S * S / N) / (N - 1.0);
        if (var < 0.0) var = 0.0;
        const double sdp = sqrt(var) + 1e-8;
        const float off = MN - (float)(1e-8 * sdp);
        const float inv = 1.0f / (MX - off);
        scal[0] = off;
        scal[1] = inv;
    }
}

__global__ __launch_bounds__(256)
void xray_normalize(float* __restrict__ outv, const float* __restrict__ scal)
{
    const int i = blockIdx.x * 256 + threadIdx.x;
    const float off = scal[0], inv = scal[1];
    outv[i] = (outv[i] - off) * inv;
}

// ---------------------------------------------------------------------------
extern "C" void kernel_launch(void* const* d_in, const int* in_sizes, int n_in,
                              void* d_out, int out_size, void* d_ws, size_t ws_size,
                              hipStream_t stream)
{
    const float* vol = (const float*)d_in[0];   // (1,1,256,256,256)
    const float* Rm  = (const float*)d_in[1];   // (1,3,3)
    const float* Tv  = (const float*)d_in[2];   // (1,3)
    const float* fc  = (const float*)d_in[3];   // (1,)
    float* outv = (float*)d_out;                // (1,1,256,256) fp32
    float* partials = (float*)d_ws;             // 1024*4 floats
    float* scal = partials + 4 * NBLK;          // 2 floats

    dim3 grid(IMG / 8, IMG / 8);
    xray_render<<<grid, 512, 0, stream>>>(vol, Rm, Tv, fc, outv, partials);
    xray_finalize<<<1, 256, 0, stream>>>(partials, scal);
    xray_normalize<<<256, 256, 0, stream>>>(outv, scal);
}